// Round 1
// baseline (286.769 us; speedup 1.0000x reference)
//
#include <hip/hip_runtime.h>

// RawISPProcessing: demosaic (bilinear 2x; flips are no-ops under the
// symmetric half-pixel grid) + folded (x2 * chflip * awb^T * ccm^T * chflip)
// 3x3 matrix + clip + gamma 1/2.2.
//
// R3: one OUTPUT row per thread (even rows: src rows j-1,j @ 0.25/0.75;
// odd rows: j,j+1 @ 0.75/0.25). Cuts live state from 8x8 to 3x8 floats
// (VGPR ~150 -> ~90) to double occupancy; the kernel was latency-bound,
// not BW-bound (HBM floor ~43us, VALU ~14us).

#define GAMMA_INV 0.45454545454545453f
#define EPS_CLIP 1e-8f

__device__ __forceinline__ float gamma_enc(float v) {
  v = fmaxf(v, EPS_CLIP);
  return exp2f(GAMMA_INV * __log2f(v));
}

// For one channel: load the 6-wide col window [im, i..i+3, ip] from source
// rows rA,rB, blend vertically with (wA,wB), then horizontal 2x -> h[8].
__device__ __forceinline__ void up2_half(const float* __restrict__ ch,
                                         int rA, int rB, float wA, float wB,
                                         int im, int i, int ip,
                                         float h[8]) {
  const int W = 512;
  const float* a = ch + rA * W;
  const float* bp = ch + rB * W;
  float4 va = *reinterpret_cast<const float4*>(a + i);
  float4 vb = *reinterpret_cast<const float4*>(bp + i);
  float v[6];
  v[0] = wA * a[im] + wB * bp[im];
  v[1] = wA * va.x + wB * vb.x;
  v[2] = wA * va.y + wB * vb.y;
  v[3] = wA * va.z + wB * vb.z;
  v[4] = wA * va.w + wB * vb.w;
  v[5] = wA * a[ip] + wB * bp[ip];
#pragma unroll
  for (int p = 0; p < 4; ++p) {
    h[2 * p]     = 0.25f * v[p]     + 0.75f * v[p + 1];
    h[2 * p + 1] = 0.75f * v[p + 1] + 0.25f * v[p + 2];
  }
}

__global__ __launch_bounds__(256) void isp_kernel(
    const float* __restrict__ pred, const float* __restrict__ gt,
    const float* __restrict__ awb, const float* __restrict__ ccm,
    float* __restrict__ out) {
  constexpr int H = 512, W = 512;
  constexpr int HW = H * W;
  constexpr long long OUT_IMG = 8LL * 3 * 1024 * 1024;

  int idx = blockIdx.x * blockDim.x + threadIdx.x;  // 2*8*1024*128 threads
  int t   = idx & 127;           // col group: out cols [8t, 8t+7]
  int oy  = (idx >> 7) & 1023;   // OUTPUT row
  int b   = (idx >> 17) & 7;     // batch
  int img = idx >> 20;           // 0=pred, 1=gt

  // Folded color matrix: out[k] = 2 * sum_e v[e] * sum_c awb[2-e][c]*ccm[c][2-k]
  const float* A  = awb + b * 9;
  const float* Cm = ccm + b * 9;
  float M[3][3];
#pragma unroll
  for (int k = 0; k < 3; ++k) {
#pragma unroll
    for (int e = 0; e < 3; ++e) {
      int ar = (2 - e) * 3;
      int cc = 2 - k;
      M[k][e] = 2.0f * (A[ar + 0] * Cm[0 + cc] +
                        A[ar + 1] * Cm[3 + cc] +
                        A[ar + 2] * Cm[6 + cc]);
    }
  }

  int j = oy >> 1;
  bool even = (oy & 1) == 0;     // wave-uniform (oy constant per wave)
  int   rA = even ? (j > 0 ? j - 1 : 0) : j;
  int   rB = even ? j : (j < H - 1 ? j + 1 : H - 1);
  float wA = even ? 0.25f : 0.75f;
  float wB = even ? 0.75f : 0.25f;

  int i  = 4 * t;
  int im = (i > 0) ? i - 1 : 0;
  int ip = (i + 4 < W) ? i + 4 : W - 1;

  const float* src = (img ? gt : pred) + (long long)b * 4 * HW;

  float r8[8], g8[8], q8[8];
  up2_half(src + 0 * HW, rA, rB, wA, wB, im, i, ip, r8);  // red
  up2_half(src + 1 * HW, rA, rB, wA, wB, im, i, ip, g8);  // Gr
  up2_half(src + 2 * HW, rA, rB, wA, wB, im, i, ip, q8);  // Gb
  // Green quad-parity combine: (even y): even x = avg, odd x = Gr;
  //                            (odd y):  even x = Gb,  odd x = avg.
  if (even) {
#pragma unroll
    for (int p = 0; p < 4; ++p)
      g8[2 * p] = 0.5f * (g8[2 * p] + q8[2 * p]);
  } else {
#pragma unroll
    for (int p = 0; p < 4; ++p) {
      g8[2 * p]     = q8[2 * p];
      g8[2 * p + 1] = 0.5f * (g8[2 * p + 1] + q8[2 * p + 1]);
    }
  }
  up2_half(src + 3 * HW, rA, rB, wA, wB, im, i, ip, q8);  // blue (reuse q8)

  int ox = 8 * t;
  float* dst = out + (long long)img * OUT_IMG;

#pragma unroll
  for (int k = 0; k < 3; ++k) {
    float o8[8];
#pragma unroll
    for (int p = 0; p < 8; ++p)
      o8[p] = gamma_enc(M[k][0] * r8[p] + M[k][1] * g8[p] + M[k][2] * q8[p]);
    long long obase = ((long long)(b * 3 + k) * 1024 + oy) * 1024 + ox;
    *reinterpret_cast<float4*>(dst + obase)     = make_float4(o8[0], o8[1], o8[2], o8[3]);
    *reinterpret_cast<float4*>(dst + obase + 4) = make_float4(o8[4], o8[5], o8[6], o8[7]);
  }
}

extern "C" void kernel_launch(void* const* d_in, const int* in_sizes, int n_in,
                              void* d_out, int out_size, void* d_ws, size_t ws_size,
                              hipStream_t stream) {
  const float* pred = (const float*)d_in[0];
  const float* gt   = (const float*)d_in[1];
  const float* awb  = (const float*)d_in[2];
  const float* ccm  = (const float*)d_in[3];
  // d_in[4] = rgb_gain: unused by the reference.
  float* out = (float*)d_out;

  const int total = 2 * 8 * 1024 * 128;  // img * batch * out-rows * col-groups
  dim3 block(256);
  dim3 grid(total / 256);
  isp_kernel<<<grid, block, 0, stream>>>(pred, gt, awb, ccm, out);
}